// Round 4
// baseline (357.743 us; speedup 1.0000x reference)
//
#include <hip/hip_runtime.h>
#include <hip/hip_bf16.h>
#include <stdint.h>

#define B_ROWS 16384
#define K_DIM  2048   // IN + H
#define H_DIM  1024
#define N_DIM  4096   // 4*H
#define KB     (K_DIM * 2)      // bytes per packed row (4096)
#define NT     (K_DIM / 64)     // 32 K-tiles of BK=64
#define BUFSZ  49152u           // one LDS buffer: A 32K + B 16K

using f32x4  = __attribute__((ext_vector_type(4))) float;
using bf16x8 = __attribute__((ext_vector_type(8))) __bf16;

// RNE float -> bf16 (inputs are finite)
__device__ __forceinline__ unsigned short f2bf(float f) {
    union { float f; unsigned u; } v; v.f = f;
    unsigned r = v.u + 0x7fffu + ((v.u >> 16) & 1u);
    return (unsigned short)(r >> 16);
}

// async global->LDS, 16B/lane. LDS dest must be wave-uniform (HW adds lane*16).
__device__ __forceinline__ void gload16(const void* g, const void* l) {
    __builtin_amdgcn_global_load_lds(
        (const __attribute__((address_space(1))) void*)g,
        (__attribute__((address_space(3))) void*)l,
        16, 0, 0);
}

__device__ __forceinline__ float rcp1p(float e) {   // 1/(1+e)
    return __builtin_amdgcn_rcpf(1.f + e);
}

// ---------------- pack kernels (unchanged, verified) ----------------
__global__ void pack_a_kernel(const float* __restrict__ x, const float* __restrict__ h0,
                              unsigned short* __restrict__ A) {
    int tid = blockIdx.x * 256 + threadIdx.x;
    int64_t idx = (int64_t)tid * 4;
    int b = (int)(idx >> 11);
    int k = (int)(idx & 2047);
    const float* src = (k < 1024) ? (x + (int64_t)b * 1024 + k)
                                  : (h0 + (int64_t)b * 1024 + (k - 1024));
    float4 v = *(const float4*)src;
    ushort4 o;
    o.x = f2bf(v.x); o.y = f2bf(v.y); o.z = f2bf(v.z); o.w = f2bf(v.w);
    *(ushort4*)(A + idx) = o;
}

__global__ void pack_w_kernel(const float* __restrict__ wi, const float* __restrict__ wh,
                              const float* __restrict__ bi, const float* __restrict__ bh,
                              unsigned short* __restrict__ W, float* __restrict__ bias) {
    int tid = blockIdx.x * 256 + threadIdx.x;
    int64_t idx = (int64_t)tid * 4;
    int r = (int)(idx >> 11);
    int k = (int)(idx & 2047);
    int h = r >> 2, g = r & 3;
    const float* src = (k < 1024)
        ? (wi + (int64_t)g * 1048576 + (int64_t)h * 1024 + k)
        : (wh + (int64_t)g * 1048576 + (int64_t)h * 1024 + (k - 1024));
    float4 v = *(const float4*)src;
    ushort4 o;
    o.x = f2bf(v.x); o.y = f2bf(v.y); o.z = f2bf(v.z); o.w = f2bf(v.w);
    *(ushort4*)(W + idx) = o;
    if (k == 0) bias[r] = bi[g * 1024 + h] + bh[g * 1024 + h];
}

// ------------- 256x128 one-barrier-per-window GEMM + fused LSTM epilogue -------------
// LDS buffer (x2): A 256x64 bf16 (kk0 @0, kk1 @16384), B 128x64 (kk0 @32768, kk1 @40960).
// st_16x32 swizzle (verified r2): subtile byte = (row&15)*64 + (col ^ ((row&8)<<2));
// staged linear-dest global_load_lds with inverse-swizzled global source.
// Window i (= half K-tile): VM3 -> BAR -> 8 ds_reads(D_i) -> 3 gloads(D_{i+2})
//                           -> lgkm(8) -> 16 MFMA(prev bank).
// Covering rule: all waves vm-wait D_i before BAR_i, reads after BAR_i (RAW safe).
// Stage depth 2 windows: region last read at i-2, drained by lgkm8_{i-1} < BAR_i (WAR safe).

#define SCHED0  __builtin_amdgcn_sched_barrier(0)
#define FENCE   asm volatile("" ::: "memory")
#define BARRIER do { FENCE; __builtin_amdgcn_s_barrier(); FENCE; } while (0)
#define WAIT_VM3   asm volatile("s_waitcnt vmcnt(3)" ::: "memory")
#define WAIT_LGKM8 asm volatile("s_waitcnt lgkmcnt(8)" ::: "memory")

__global__ __launch_bounds__(512, 2) void lstm_gemm_fused(
    const unsigned short* __restrict__ A, const unsigned short* __restrict__ W,
    const float* __restrict__ bias, const float* __restrict__ c0,
    float* __restrict__ ht, float* __restrict__ ct)
{
    __shared__ char sm[98304];

    const int tid = threadIdx.x;
    const int l   = tid & 63;
    const int w   = tid >> 6;         // wave 0..7
    const int wm  = w >> 1;           // 0..3  (row quarter: 64 rows)
    const int wn  = w & 1;            // 0..1  (col half: 64 cols)

    // XCD-aware bijective swizzle (2048 blocks, %8==0)
    const int bid = blockIdx.x;
    const int nid = (bid & 7) * 256 + (bid >> 3);
    const int bm  = nid >> 5;         // 0..63 (M tiles of 256)
    const int bn  = nid & 31;         // 0..31 (N tiles of 128)

    f32x4 acc[4][4];
#pragma unroll
    for (int i = 0; i < 4; ++i)
#pragma unroll
        for (int j = 0; j < 4; ++j) acc[i][j] = (f32x4){0.f, 0.f, 0.f, 0.f};

    // ---- staging source addressing (inverse-swizzled) ----
    const int srow = w * 16 + (l >> 2);                 // 0..127
    const int scb  = ((l & 3) << 4) ^ (l & 32);
    const char* Asrc = (const char*)A + (size_t)(bm * 256 + srow) * KB + scb;
    const char* Wsrc = (const char*)W + (size_t)(bn * 128 + srow) * KB + scb;
    const uint32_t wL = (uint32_t)w * 1024u;            // wave-uniform LDS dest part

    // A kk-chunk (16KB = 2 gloads: rows 0-127, 128-255); B kk-chunk (8KB = 1 gload)
#define STAGE3(TS, KK, BOFF) do { \
    const char* sa_ = Asrc + (size_t)(TS) * 128 + (KK) * 64; \
    const char* sb_ = Wsrc + (size_t)(TS) * 128 + (KK) * 64; \
    gload16(sa_,            sm + (BOFF) + (KK) * 16384u + wL); \
    gload16(sa_ + 128 * KB, sm + (BOFF) + (KK) * 16384u + 8192u + wL); \
    gload16(sb_,            sm + (BOFF) + 32768u + (KK) * 8192u + wL); \
} while (0)

    // ---- fragment read addressing (swizzled) ----
    const int rr = l & 15, kg = l >> 4;
    const uint32_t loff = (uint32_t)rr * 64u + (((uint32_t)kg * 16u) ^ (uint32_t)((rr & 8) << 2));
    const uint32_t Ard = (uint32_t)wm * 4096u + loff;             // + KK*16384 + mf*1024
    const uint32_t Brd = 32768u + (uint32_t)wn * 4096u + loff;    // + KK*8192  + nf*1024

    bf16x8 aA[4], bA[4], aB[4], bB[4];

#define READS(BOFF, KK, AR, BR) do { \
    _Pragma("unroll") \
    for (int mf_ = 0; mf_ < 4; ++mf_) \
        AR[mf_] = *(const bf16x8*)(sm + (BOFF) + (KK) * 16384u + Ard + mf_ * 1024u); \
    _Pragma("unroll") \
    for (int nf_ = 0; nf_ < 4; ++nf_) \
        BR[nf_] = *(const bf16x8*)(sm + (BOFF) + (KK) * 8192u + Brd + nf_ * 1024u); \
} while (0)

#define MFMA16(AR, BR) do { \
    SCHED0; __builtin_amdgcn_s_setprio(1); \
    _Pragma("unroll") \
    for (int mf_ = 0; mf_ < 4; ++mf_) \
        _Pragma("unroll") \
        for (int nf_ = 0; nf_ < 4; ++nf_) \
            acc[mf_][nf_] = __builtin_amdgcn_mfma_f32_16x16x32_bf16( \
                AR[mf_], BR[nf_], acc[mf_][nf_], 0, 0, 0); \
    __builtin_amdgcn_s_setprio(0); SCHED0; \
} while (0)

    // ---- prologue ----
    STAGE3(0, 0, 0u);                 // D_0           (3 in flight)
    STAGE3(0, 1, 0u);                 // D_1           (6)
    // window 0 (T=0, kk=0): no MFMA yet
    WAIT_VM3;                         // D_0 landed (own wave)
    BARRIER;                          // all waves vm-waited
    READS(0u, 0, aA, bA);             // D_0 -> bank A
    STAGE3(1, 0, BUFSZ);              // D_2           (6)
    // window 1 (T=0, kk=1):
    WAIT_VM3;                         // D_1 landed
    BARRIER;
    READS(0u, 1, aB, bB);             // D_1 -> bank B
    STAGE3(1, 1, BUFSZ);              // D_3           (6)
    SCHED0; WAIT_LGKM8; SCHED0;       // bank A reads retired
    MFMA16(aA, bA);                   // consume (0,0)

    // ---- main loop: tiles T=1..31, two windows each ----
#define DO_TILE(CUR, NXT, T) do { \
    const int st_ = ((T) + 1 < NT) ? (T) + 1 : NT - 1; \
    /* window 2T: read (T,0), stage (T+1,0), mfma (T-1,1) */ \
    WAIT_VM3; \
    BARRIER; \
    READS(CUR, 0, aA, bA); \
    STAGE3(st_, 0, NXT); \
    SCHED0; WAIT_LGKM8; SCHED0; \
    MFMA16(aB, bB); \
    /* window 2T+1: read (T,1), stage (T+1,1), mfma (T,0) */ \
    WAIT_VM3; \
    BARRIER; \
    READS(CUR, 1, aB, bB); \
    STAGE3(st_, 1, NXT); \
    SCHED0; WAIT_LGKM8; SCHED0; \
    MFMA16(aA, bA); \
} while (0)

#pragma unroll 1
    for (int tt = 1; tt < NT; tt += 2) {
        DO_TILE(BUFSZ, 0u, tt);
        if (tt + 1 < NT) DO_TILE(0u, BUFSZ, tt + 1);
    }

    // final MFMA: bank B holds (31,1)
    asm volatile("s_waitcnt lgkmcnt(0)" ::: "memory");
    SCHED0;
    MFMA16(aB, bB);

    // ---- fused LSTM epilogue ----
    asm volatile("s_waitcnt vmcnt(0) lgkmcnt(0)" ::: "memory");
    BARRIER;

    float* ep = (float*)(void*)sm + w * 1088;   // 16 rows x 68 floats per wave
    const int hbase = bn * 32 + wn * 16;
    const int rbase = bm * 256 + wm * 64;

#pragma unroll
    for (int mf = 0; mf < 4; ++mf) {
        // scatter acc slice (16 rows x 64 cols) to LDS, padded stride 68
#pragma unroll
        for (int nf = 0; nf < 4; ++nf)
#pragma unroll
            for (int r = 0; r < 4; ++r)
                ep[((l >> 4) * 4 + r) * 68 + nf * 16 + (l & 15)] = acc[mf][nf][r];

        // gather: lane -> (row, h); cols 4h..4h+3 = gates f,i,o,g
#pragma unroll
        for (int it = 0; it < 4; ++it) {
            const int row = (l >> 4) + it * 4;
            const int hs  = l & 15;
            f32x4 z = *(const f32x4*)(ep + row * 68 + hs * 4);
            const int hg = hbase + hs;
            const float4 bz = ((const float4*)bias)[hg];
            const int brow = rbase + mf * 16 + row;

            float zf = z.x + bz.x;
            float zi = z.y + bz.y;
            float zo = z.z + bz.z;
            float zg = z.w + bz.w;

            float fg = rcp1p(__expf(-zf));                   // sigmoid
            float ig = rcp1p(__expf(-zi));
            float og = rcp1p(__expf(-zo));
            float gg = 2.f * rcp1p(__expf(-2.f * zg)) - 1.f; // tanh

            int64_t oi = (int64_t)brow * H_DIM + hg;
            float c  = fg * c0[oi] + ig * gg;
            float hh = og * (2.f * rcp1p(__expf(-2.f * c)) - 1.f);
            ct[oi] = c;
            ht[oi] = hh;
        }
    }
}

extern "C" void kernel_launch(void* const* d_in, const int* in_sizes, int n_in,
                              void* d_out, int out_size, void* d_ws, size_t ws_size,
                              hipStream_t stream) {
    const float* x  = (const float*)d_in[0];
    const float* h0 = (const float*)d_in[1];
    const float* c0 = (const float*)d_in[2];
    const float* wi = (const float*)d_in[3];
    const float* bi = (const float*)d_in[4];
    const float* wh = (const float*)d_in[5];
    const float* bh = (const float*)d_in[6];

    float* ht = (float*)d_out;
    float* ct = ht + (int64_t)B_ROWS * H_DIM;

    char* ws = (char*)d_ws;
    unsigned short* A  = (unsigned short*)ws;                       // 64 MiB
    unsigned short* Wp = (unsigned short*)(ws + (64u << 20));       // 16 MiB
    float*          bs = (float*)(ws + (80u << 20));                // 16 KiB

    pack_a_kernel<<<32768, 256, 0, stream>>>(x, h0, A);
    pack_w_kernel<<<8192, 256, 0, stream>>>(wi, wh, bi, bh, Wp, bs);

    lstm_gemm_fused<<<2048, 512, 0, stream>>>(A, Wp, bs, c0, ht, ct);
}

// Round 5
// 310.980 us; speedup vs baseline: 1.1504x; 1.1504x over previous
//
#include <hip/hip_runtime.h>
#include <hip/hip_bf16.h>
#include <stdint.h>

#define B_ROWS 16384
#define K_DIM  2048   // IN + H
#define H_DIM  1024
#define N_DIM  4096   // 4*H
#define KB     (K_DIM * 2)      // bytes per packed row (4096)
#define NT     (K_DIM / 64)     // 32 K-tiles of BK=64
#define BUFSZ  65536u           // one LDS buffer: A 32K + B 32K

using f32x4  = __attribute__((ext_vector_type(4))) float;
using bf16x8 = __attribute__((ext_vector_type(8))) __bf16;

// RNE float -> bf16 (inputs are finite)
__device__ __forceinline__ unsigned short f2bf(float f) {
    union { float f; unsigned u; } v; v.f = f;
    unsigned r = v.u + 0x7fffu + ((v.u >> 16) & 1u);
    return (unsigned short)(r >> 16);
}

// async global->LDS, 16B/lane. LDS dest must be wave-uniform (HW adds lane*16).
__device__ __forceinline__ void gload16(const void* g, const void* l) {
    __builtin_amdgcn_global_load_lds(
        (const __attribute__((address_space(1))) void*)g,
        (__attribute__((address_space(3))) void*)l,
        16, 0, 0);
}

__device__ __forceinline__ float rcp1p(float e) {   // 1/(1+e)
    return __builtin_amdgcn_rcpf(1.f + e);
}

// ---------------- pack kernels (unchanged, verified) ----------------
__global__ void pack_a_kernel(const float* __restrict__ x, const float* __restrict__ h0,
                              unsigned short* __restrict__ A) {
    int tid = blockIdx.x * 256 + threadIdx.x;
    int64_t idx = (int64_t)tid * 4;
    int b = (int)(idx >> 11);
    int k = (int)(idx & 2047);
    const float* src = (k < 1024) ? (x + (int64_t)b * 1024 + k)
                                  : (h0 + (int64_t)b * 1024 + (k - 1024));
    float4 v = *(const float4*)src;
    ushort4 o;
    o.x = f2bf(v.x); o.y = f2bf(v.y); o.z = f2bf(v.z); o.w = f2bf(v.w);
    *(ushort4*)(A + idx) = o;
}

__global__ void pack_w_kernel(const float* __restrict__ wi, const float* __restrict__ wh,
                              const float* __restrict__ bi, const float* __restrict__ bh,
                              unsigned short* __restrict__ W, float* __restrict__ bias) {
    int tid = blockIdx.x * 256 + threadIdx.x;
    int64_t idx = (int64_t)tid * 4;
    int r = (int)(idx >> 11);
    int k = (int)(idx & 2047);
    int h = r >> 2, g = r & 3;
    const float* src = (k < 1024)
        ? (wi + (int64_t)g * 1048576 + (int64_t)h * 1024 + k)
        : (wh + (int64_t)g * 1048576 + (int64_t)h * 1024 + (k - 1024));
    float4 v = *(const float4*)src;
    ushort4 o;
    o.x = f2bf(v.x); o.y = f2bf(v.y); o.z = f2bf(v.z); o.w = f2bf(v.w);
    *(ushort4*)(W + idx) = o;
    if (k == 0) bias[r] = bi[g * 1024 + h] + bh[g * 1024 + h];
}

// -------- 256x256 quadrant-phase GEMM (m201-faithful) + fused LSTM epilogue --------
// LDS buffer (x2 @ 0 / 65536): A kk0 @0 (16K), A kk1 @16384, B kk0 @32768, B kk1 @49152.
// kk-half chunk = 16K = rows 0-127 (@+0) and 128-255 (@+8192), 8 subtiles/chunk.
// st_16x32 swizzle (verified r2): subtile byte = (row&15)*64 + (col ^ ((row&8)<<2));
// staged linear-dest global_load_lds with inverse-swizzled global source.
// Per K-tile 4 phases: {rd A-lo[4]+B[4]; stage 2; MFMA mf0-3} {rd A-hi[4]; stage 2;
// MFMA mf4-7; vmcnt(4)} x2 kk. vmcnt(4) at P1/P3 lands the kk-half read 2 phases later.

#define SCHED0  __builtin_amdgcn_sched_barrier(0)
#define FENCE   asm volatile("" ::: "memory")
#define BAR     __builtin_amdgcn_s_barrier()

#define PH_PRE  do { FENCE; BAR; \
                     asm volatile("s_waitcnt lgkmcnt(0)" ::: "memory"); \
                     SCHED0; __builtin_amdgcn_s_setprio(1); } while (0)
#define PH_POST do { __builtin_amdgcn_s_setprio(0); SCHED0; FENCE; BAR; } while (0)
#define PH_POST_V do { __builtin_amdgcn_s_setprio(0); SCHED0; \
                       asm volatile("s_waitcnt vmcnt(4)" ::: "memory"); \
                       SCHED0; FENCE; BAR; } while (0)

__global__ __launch_bounds__(512, 2) void lstm_gemm_fused(
    const unsigned short* __restrict__ A, const unsigned short* __restrict__ W,
    const float* __restrict__ bias, const float* __restrict__ c0,
    float* __restrict__ ht, float* __restrict__ ct)
{
    __shared__ char sm[131072];

    const int tid = threadIdx.x;
    const int l   = tid & 63;
    const int w   = tid >> 6;         // wave 0..7
    const int wm  = w >> 2;           // 0..1  (row half: 128 rows)
    const int wn  = w & 3;            // 0..3  (col quarter: 64 cols)

    // XCD-aware bijective swizzle (1024 blocks, %8==0)
    const int bid = blockIdx.x;
    const int nid = (bid & 7) * 128 + (bid >> 3);
    const int bm  = nid >> 4;         // 0..63 (M tiles)
    const int bn  = nid & 15;         // 0..15 (N tiles)

    f32x4 acc[8][4];
#pragma unroll
    for (int i = 0; i < 8; ++i)
#pragma unroll
        for (int j = 0; j < 4; ++j) acc[i][j] = (f32x4){0.f, 0.f, 0.f, 0.f};

    // ---- staging source addressing (inverse-swizzled) ----
    const int srow = w * 16 + (l >> 2);                 // 0..127
    const int scb  = ((l & 3) << 4) ^ (l & 32);
    const char* Asrc = (const char*)A + (size_t)(bm * 256 + srow) * KB + scb;
    const char* Wsrc = (const char*)W + (size_t)(bn * 256 + srow) * KB + scb;
    const uint32_t wL = (uint32_t)w * 1024u;            // wave-uniform LDS dest part

    // one kk-half of A or B = 16K = 2 gloads (rows 0-127, 128-255)
#define STAGE_A(TS, KK, BOFF) do { \
    const char* s_ = Asrc + (size_t)(TS) * 128 + (KK) * 64; \
    gload16(s_,            sm + (BOFF) + (KK) * 16384u + wL); \
    gload16(s_ + 128 * KB, sm + (BOFF) + (KK) * 16384u + 8192u + wL); \
} while (0)
#define STAGE_B(TS, KK, BOFF) do { \
    const char* s_ = Wsrc + (size_t)(TS) * 128 + (KK) * 64; \
    gload16(s_,            sm + (BOFF) + 32768u + (KK) * 16384u + wL); \
    gload16(s_ + 128 * KB, sm + (BOFF) + 32768u + (KK) * 16384u + 8192u + wL); \
} while (0)

    // ---- fragment read addressing (swizzled) ----
    const int rr = l & 15, kg = l >> 4;
    const uint32_t loff = (uint32_t)rr * 64u + (((uint32_t)kg * 16u) ^ (uint32_t)((rr & 8) << 2));
    const uint32_t Ard = (uint32_t)wm * 8192u + loff;             // + BOFF + KK*16384 + mf*1024
    const uint32_t Brd = 32768u + (uint32_t)wn * 4096u + loff;    // + BOFF + KK*16384 + nf*1024

    bf16x8 aL[4], aH[4], bb[4];

#define RD_A4(BOFF, KK, MB, ARR) do { \
    _Pragma("unroll") \
    for (int i_ = 0; i_ < 4; ++i_) \
        ARR[i_] = *(const bf16x8*)(sm + (BOFF) + (KK) * 16384u + Ard + ((MB) + i_) * 1024u); \
} while (0)
#define RD_B4(BOFF, KK) do { \
    _Pragma("unroll") \
    for (int i_ = 0; i_ < 4; ++i_) \
        bb[i_] = *(const bf16x8*)(sm + (BOFF) + (KK) * 16384u + Brd + i_ * 1024u); \
} while (0)

#define MFMA16H(ARR, MB) do { \
    _Pragma("unroll") \
    for (int mf_ = 0; mf_ < 4; ++mf_) \
        _Pragma("unroll") \
        for (int nf_ = 0; nf_ < 4; ++nf_) \
            acc[(MB) + mf_][nf_] = __builtin_amdgcn_mfma_f32_16x16x32_bf16( \
                ARR[mf_], bb[nf_], acc[(MB) + mf_][nf_], 0, 0, 0); \
} while (0)

    // ---- prologue: stage tile 0 fully; wait its kk0 half ----
    STAGE_A(0, 0, 0u); STAGE_B(0, 0, 0u);   // 4 loads (kk0)
    STAGE_A(0, 1, 0u); STAGE_B(0, 1, 0u);   // 4 loads (kk1)
    asm volatile("s_waitcnt vmcnt(4)" ::: "memory");
    SCHED0; FENCE; BAR;

    // ---- main loop: 4 quadrant phases per tile, stage 2 gloads/phase ----
#define DO_TILE(CUR, NXT, T) do { \
    const int st_ = ((T) + 1 < NT) ? (T) + 1 : NT - 1; \
    /* P0: kk0, mf 0-3 */ \
    RD_A4(CUR, 0, 0, aL); RD_B4(CUR, 0); \
    STAGE_A(st_, 0, NXT); \
    PH_PRE; MFMA16H(aL, 0); PH_POST; \
    /* P1: kk0, mf 4-7 (reuse bb) */ \
    RD_A4(CUR, 0, 4, aH); \
    STAGE_B(st_, 0, NXT); \
    PH_PRE; MFMA16H(aH, 4); PH_POST_V; \
    /* P2: kk1, mf 0-3 */ \
    RD_A4(CUR, 1, 0, aL); RD_B4(CUR, 1); \
    STAGE_A(st_, 1, NXT); \
    PH_PRE; MFMA16H(aL, 0); PH_POST; \
    /* P3: kk1, mf 4-7 */ \
    RD_A4(CUR, 1, 4, aH); \
    STAGE_B(st_, 1, NXT); \
    PH_PRE; MFMA16H(aH, 4); PH_POST_V; \
} while (0)

#pragma unroll 1
    for (int tt = 0; tt < NT; tt += 2) {
        DO_TILE(0u, BUFSZ, tt);
        DO_TILE(BUFSZ, 0u, tt + 1);
    }

    // ---- fused LSTM epilogue ----
    asm volatile("s_waitcnt vmcnt(0) lgkmcnt(0)" ::: "memory");
    FENCE; BAR;

    float* ep = (float*)(void*)sm + w * 1088;   // 16 rows x 68 floats per wave
    const int hbase = bn * 64 + wn * 16;
    const int rbase = bm * 256 + wm * 128;

#pragma unroll
    for (int mf = 0; mf < 8; ++mf) {
        // scatter acc slice (16 rows x 64 cols) to LDS, padded stride 68
#pragma unroll
        for (int nf = 0; nf < 4; ++nf)
#pragma unroll
            for (int r = 0; r < 4; ++r)
                ep[((l >> 4) * 4 + r) * 68 + nf * 16 + (l & 15)] = acc[mf][nf][r];

        // gather: lane -> (row, h); cols 4h..4h+3 = gates f,i,o,g
#pragma unroll
        for (int it = 0; it < 4; ++it) {
            const int row = (l >> 4) + it * 4;
            const int hs  = l & 15;
            f32x4 z = *(const f32x4*)(ep + row * 68 + hs * 4);
            const int hg = hbase + hs;
            const float4 bz = ((const float4*)bias)[hg];
            const int brow = rbase + mf * 16 + row;

            float zf = z.x + bz.x;
            float zi = z.y + bz.y;
            float zo = z.z + bz.z;
            float zg = z.w + bz.w;

            float fg = rcp1p(__expf(-zf));                   // sigmoid
            float ig = rcp1p(__expf(-zi));
            float og = rcp1p(__expf(-zo));
            float gg = 2.f * rcp1p(__expf(-2.f * zg)) - 1.f; // tanh

            int64_t oi = (int64_t)brow * H_DIM + hg;
            float c  = fg * c0[oi] + ig * gg;
            float hh = og * (2.f * rcp1p(__expf(-2.f * c)) - 1.f);
            ct[oi] = c;
            ht[oi] = hh;
        }
    }
}

extern "C" void kernel_launch(void* const* d_in, const int* in_sizes, int n_in,
                              void* d_out, int out_size, void* d_ws, size_t ws_size,
                              hipStream_t stream) {
    const float* x  = (const float*)d_in[0];
    const float* h0 = (const float*)d_in[1];
    const float* c0 = (const float*)d_in[2];
    const float* wi = (const float*)d_in[3];
    const float* bi = (const float*)d_in[4];
    const float* wh = (const float*)d_in[5];
    const float* bh = (const float*)d_in[6];

    float* ht = (float*)d_out;
    float* ct = ht + (int64_t)B_ROWS * H_DIM;

    char* ws = (char*)d_ws;
    unsigned short* A  = (unsigned short*)ws;                       // 64 MiB
    unsigned short* Wp = (unsigned short*)(ws + (64u << 20));       // 16 MiB
    float*          bs = (float*)(ws + (80u << 20));                // 16 KiB

    pack_a_kernel<<<32768, 256, 0, stream>>>(x, h0, A);
    pack_w_kernel<<<8192, 256, 0, stream>>>(wi, wh, bi, bh, Wp, bs);

    lstm_gemm_fused<<<1024, 512, 0, stream>>>(A, Wp, bs, c0, ht, ct);
}